// Round 1
// baseline (531.982 us; speedup 1.0000x reference)
//
#include <hip/hip_runtime.h>
#include <cmath>

// SwinBlock: B=8, H=W=256, C=96, WS=8, SHIFT=4, HEADS=3, hd=32
// d_in: x, n1g, n1b, qkv_w, qkv_b, proj_w, proj_b, ls1, n2g, n2b, w1, b1, w2, b2, ls2

typedef __bf16 bf16_t;
typedef __bf16 bf16x8 __attribute__((ext_vector_type(8)));
typedef float  f32x4  __attribute__((ext_vector_type(4)));

#define KP  104   // padded row length (bf16) for K=96 operands; 208B stride, 16B aligned
#define VTP 72    // vT row pad (token dim)
#define PSP 72    // P row pad

// d_ws bf16 layout (element offsets):
//   [0)      qkv_w^T  [288][96]
//   [27648)  proj_w^T [96][96]      (contiguous with qkv_w^T as a [384][96] block)
//   [36864)  mlp_w1^T [384][96]
//   [73728)  mlp_w2^T [96][384]
//   total 110592 elems = 221184 B

__device__ __forceinline__ f32x4 mfma16(bf16x8 a, bf16x8 b, f32x4 c) {
    return __builtin_amdgcn_mfma_f32_16x16x32_bf16(a, b, c, 0, 0, 0);
}

__global__ void prep_kernel(const float* __restrict__ qkv_w, const float* __restrict__ proj_w,
                            const float* __restrict__ w1,    const float* __restrict__ w2,
                            bf16_t* __restrict__ ws) {
    int i = blockIdx.x * 256 + threadIdx.x;
    if (i >= 110592) return;
    float v;
    if (i < 27648)      { int n = i / 96, k = i - n * 96;              v = qkv_w[k * 288 + n]; }
    else if (i < 36864) { int j = i - 27648; int n = j / 96,  k = j - n * 96;  v = proj_w[k * 96 + n]; }
    else if (i < 73728) { int j = i - 36864; int n = j / 96,  k = j - n * 96;  v = w1[k * 384 + n]; }
    else                { int j = i - 73728; int n = j / 384, k = j - n * 384; v = w2[k * 96 + n]; }
    ws[i] = (bf16_t)v;
}

// ---------------- Kernel 1: LN1 + windowed attention + proj + residual -> x1 (d_out) -------------
// persistent: grid=256 blocks, 256 threads (4 waves), each block loops 32 windows.
__global__ void __launch_bounds__(256, 1) attn_kernel(
        const float* __restrict__ x,
        const float* __restrict__ n1g, const float* __restrict__ n1b,
        const float* __restrict__ qkv_b, const float* __restrict__ proj_b,
        const float* __restrict__ ls1,
        const bf16_t* __restrict__ wsb,
        float* __restrict__ x1out) {
    extern __shared__ bf16_t sm1[];
    bf16_t* wT = sm1;                 // [384][KP]: rows 0..287 qkv_w^T, 288..383 proj_w^T
    bf16_t* hs = wT + 384 * KP;       // [64][KP]   LN1 output
    bf16_t* qs = hs + 64 * KP;        // [64][KP]   q (pre-scaled)
    bf16_t* ks = qs + 64 * KP;        // [64][KP]   k
    bf16_t* vT = ks + 64 * KP;        // [96][VTP]  v transposed (ch-major)
    bf16_t* Ps = vT + 96 * VTP;       // [64][PSP]  softmax probs
    bf16_t* os = Ps + 64 * PSP;       // [64][KP]   attention out
    // total 78080 bf16 = 156160 B

    const int tid  = threadIdx.x;
    const int lane = tid & 63;
    const int wid  = tid >> 6;        // 0..3, wave owns rows 16*wid..+15
    const int lm   = lane & 15;
    const int lg   = lane >> 4;

    // stage weights once (36864 bf16 = [384][96] compact -> [384][KP] padded)
    #pragma unroll
    for (int it = 0; it < 18; ++it) {
        int idx = it * 2048 + tid * 8;
        int n = idx / 96, k = idx - n * 96;
        *(bf16x8*)(wT + n * KP + k) = *(const bf16x8*)(wsb + idx);
    }
    __syncthreads();

    for (int w = blockIdx.x; w < 8192; w += gridDim.x) {
        const int b = w >> 10, wh = (w >> 5) & 31, ww = w & 31;

        // ---- phase 1: load x, LN1 -> hs (bf16). 4 threads per token, 24 ch each
        {
            int tok = tid >> 2, q4 = tid & 3;
            int r = tok >> 3, c = tok & 7;
            int gr = (wh * 8 + r + 4) & 255;
            int gc = (ww * 8 + c + 4) & 255;
            const float* xp = x + (((size_t)(b * 256 + gr)) * 256 + gc) * 96 + q4 * 24;
            float v[24];
            #pragma unroll
            for (int g = 0; g < 6; ++g) {
                float4 t = *(const float4*)(xp + g * 4);
                v[g*4+0] = t.x; v[g*4+1] = t.y; v[g*4+2] = t.z; v[g*4+3] = t.w;
            }
            float s = 0.f, ss = 0.f;
            #pragma unroll
            for (int j = 0; j < 24; ++j) { s += v[j]; ss += v[j] * v[j]; }
            s  += __shfl_xor(s, 1);  s  += __shfl_xor(s, 2);
            ss += __shfl_xor(ss, 1); ss += __shfl_xor(ss, 2);
            float mean = s * (1.f / 96.f);
            float rinv = rsqrtf(ss * (1.f / 96.f) - mean * mean + 1e-5f);
            #pragma unroll
            for (int g = 0; g < 3; ++g) {
                bf16x8 pk;
                #pragma unroll
                for (int j = 0; j < 8; ++j) {
                    int ch = q4 * 24 + g * 8 + j;
                    pk[j] = (bf16_t)((v[g*8+j] - mean) * rinv * n1g[ch] + n1b[ch]);
                }
                *(bf16x8*)(hs + tok * KP + q4 * 24 + g * 8) = pk;
            }
        }
        __syncthreads();

        // ---- qkv GEMM: A = hs rows [16w..16w+15], B = wT rows 0..287 (qkv_w^T)
        {
            bf16x8 af[3];
            #pragma unroll
            for (int s = 0; s < 3; ++s)
                af[s] = *(const bf16x8*)(hs + (wid * 16 + lm) * KP + s * 32 + lg * 8);
            f32x4 acc[18];
            #pragma unroll
            for (int ct = 0; ct < 18; ++ct) acc[ct] = (f32x4){0.f, 0.f, 0.f, 0.f};
            #pragma unroll
            for (int ct = 0; ct < 18; ++ct) {
                #pragma unroll
                for (int s = 0; s < 3; ++s) {
                    bf16x8 bf = *(const bf16x8*)(wT + (ct * 16 + lm) * KP + s * 32 + lg * 8);
                    acc[ct] = mfma16(af[s], bf, acc[ct]);
                }
            }
            const float qscale = 0.17677669529663688f;   // 1/sqrt(32), folded into q
            #pragma unroll
            for (int ct = 0; ct < 18; ++ct) {
                int col = ct * 16 + lm;
                float bias = qkv_b[col];
                #pragma unroll
                for (int j = 0; j < 4; ++j) {
                    int row = wid * 16 + lg * 4 + j;
                    float val = acc[ct][j] + bias;
                    if (ct < 6)        qs[row * KP + col]             = (bf16_t)(val * qscale);
                    else if (ct < 12)  ks[row * KP + (col - 96)]      = (bf16_t)val;
                    else               vT[(col - 192) * VTP + row]    = (bf16_t)val;
                }
            }
        }
        __syncthreads();

        // ---- attention, per head; wave handles its own 16 query rows
        #pragma unroll
        for (int h = 0; h < 3; ++h) {
            bf16x8 qf = *(const bf16x8*)(qs + (wid * 16 + lm) * KP + h * 32 + lg * 8);
            f32x4 sacc[4];
            #pragma unroll
            for (int nt = 0; nt < 4; ++nt) sacc[nt] = (f32x4){0.f, 0.f, 0.f, 0.f};
            #pragma unroll
            for (int nt = 0; nt < 4; ++nt) {
                bf16x8 kf = *(const bf16x8*)(ks + (nt * 16 + lm) * KP + h * 32 + lg * 8);
                sacc[nt] = mfma16(qf, kf, sacc[nt]);
            }
            // softmax: row r = 16*wid + lg*4 + j lives in 16 lanes (lg group) x 4 tiles
            float inv[4];
            #pragma unroll
            for (int j = 0; j < 4; ++j) {
                float m0 = fmaxf(fmaxf(sacc[0][j], sacc[1][j]), fmaxf(sacc[2][j], sacc[3][j]));
                m0 = fmaxf(m0, __shfl_xor(m0, 1));
                m0 = fmaxf(m0, __shfl_xor(m0, 2));
                m0 = fmaxf(m0, __shfl_xor(m0, 4));
                m0 = fmaxf(m0, __shfl_xor(m0, 8));
                float t = 0.f;
                #pragma unroll
                for (int nt = 0; nt < 4; ++nt) {
                    float e = __expf(sacc[nt][j] - m0);
                    sacc[nt][j] = e;
                    t += e;
                }
                t += __shfl_xor(t, 1);
                t += __shfl_xor(t, 2);
                t += __shfl_xor(t, 4);
                t += __shfl_xor(t, 8);
                inv[j] = 1.f / t;
            }
            #pragma unroll
            for (int nt = 0; nt < 4; ++nt)
                #pragma unroll
                for (int j = 0; j < 4; ++j)
                    Ps[(wid * 16 + lg * 4 + j) * PSP + nt * 16 + lm] = (bf16_t)(sacc[nt][j] * inv[j]);

            // PV: A = Ps rows (own), B = vT
            f32x4 oacc[2];
            oacc[0] = (f32x4){0.f, 0.f, 0.f, 0.f};
            oacc[1] = (f32x4){0.f, 0.f, 0.f, 0.f};
            #pragma unroll
            for (int k2 = 0; k2 < 2; ++k2) {
                bf16x8 pf = *(const bf16x8*)(Ps + (wid * 16 + lm) * PSP + k2 * 32 + lg * 8);
                #pragma unroll
                for (int c2 = 0; c2 < 2; ++c2) {
                    bf16x8 vf = *(const bf16x8*)(vT + (h * 32 + c2 * 16 + lm) * VTP + k2 * 32 + lg * 8);
                    oacc[c2] = mfma16(pf, vf, oacc[c2]);
                }
            }
            #pragma unroll
            for (int c2 = 0; c2 < 2; ++c2)
                #pragma unroll
                for (int j = 0; j < 4; ++j)
                    os[(wid * 16 + lg * 4 + j) * KP + h * 32 + c2 * 16 + lm] = (bf16_t)(oacc[c2][j]);
        }

        // ---- proj + residual: x1 = x + ls1 * (o @ proj_w + proj_b); write fp32 to d_out
        {
            bf16x8 af[3];
            #pragma unroll
            for (int s = 0; s < 3; ++s)
                af[s] = *(const bf16x8*)(os + (wid * 16 + lm) * KP + s * 32 + lg * 8);
            f32x4 pacc[6];
            #pragma unroll
            for (int ct = 0; ct < 6; ++ct) pacc[ct] = (f32x4){0.f, 0.f, 0.f, 0.f};
            #pragma unroll
            for (int ct = 0; ct < 6; ++ct) {
                #pragma unroll
                for (int s = 0; s < 3; ++s) {
                    bf16x8 bf = *(const bf16x8*)(wT + (288 + ct * 16 + lm) * KP + s * 32 + lg * 8);
                    pacc[ct] = mfma16(af[s], bf, pacc[ct]);
                }
            }
            #pragma unroll
            for (int ct = 0; ct < 6; ++ct) {
                int col = ct * 16 + lm;
                float pb = proj_b[col];
                float l1 = ls1[col];
                #pragma unroll
                for (int j = 0; j < 4; ++j) {
                    int row = wid * 16 + lg * 4 + j;
                    int r = row >> 3, c = row & 7;
                    int gr = (wh * 8 + r + 4) & 255;
                    int gc = (ww * 8 + c + 4) & 255;
                    size_t a = (((size_t)(b * 256 + gr)) * 256 + gc) * 96 + col;
                    x1out[a] = x[a] + (pacc[ct][j] + pb) * l1;
                }
            }
        }
        __syncthreads();   // protect hs/qs/ks/vT before next window overwrites
    }
}

// ---------------- Kernel 2: LN2 + MLP (gelu) + residual, in-place on d_out ----------------------
// grid=2048 blocks x 512 threads (8 waves); 256 tokens/block; 4 chunks of 96 mid-channels.
__global__ void __launch_bounds__(512, 1) mlp_kernel(
        const float* __restrict__ n2g, const float* __restrict__ n2b,
        const float* __restrict__ b1,  const float* __restrict__ b2,
        const float* __restrict__ ls2,
        const bf16_t* __restrict__ wsb,
        float* io) {
    extern __shared__ bf16_t sm2[];
    bf16_t* hs2 = sm2;                 // [256][KP] LN2 output
    bf16_t* mid = hs2 + 256 * KP;      // [256][KP] gelu(mid) chunk
    bf16_t* wb1 = mid + 256 * KP;      // [96][KP]  w1^T chunk
    bf16_t* wb2 = wb1 + 96 * KP;       // [96][KP]  w2^T chunk
    // total 73216 bf16 = 146432 B

    const int tid  = threadIdx.x;
    const int lane = tid & 63;
    const int wid  = tid >> 6;         // 0..7, wave owns rows 32*wid..+31
    const int lm   = lane & 15;
    const int lg   = lane >> 4;
    const size_t tok0 = (size_t)blockIdx.x * 256;

    // ---- LN2: 2 threads per token, 48 ch each
    {
        int tok = tid >> 1, hf = tid & 1;
        const float* xp = io + (tok0 + tok) * 96 + hf * 48;
        float v[48];
        #pragma unroll
        for (int g = 0; g < 12; ++g) {
            float4 t = *(const float4*)(xp + g * 4);
            v[g*4+0] = t.x; v[g*4+1] = t.y; v[g*4+2] = t.z; v[g*4+3] = t.w;
        }
        float s = 0.f, ss = 0.f;
        #pragma unroll
        for (int j = 0; j < 48; ++j) { s += v[j]; ss += v[j] * v[j]; }
        s += __shfl_xor(s, 1); ss += __shfl_xor(ss, 1);
        float mean = s * (1.f / 96.f);
        float rinv = rsqrtf(ss * (1.f / 96.f) - mean * mean + 1e-5f);
        #pragma unroll
        for (int g = 0; g < 6; ++g) {
            bf16x8 pk;
            #pragma unroll
            for (int j = 0; j < 8; ++j) {
                int ch = hf * 48 + g * 8 + j;
                pk[j] = (bf16_t)((v[g*8+j] - mean) * rinv * n2g[ch] + n2b[ch]);
            }
            *(bf16x8*)(hs2 + tok * KP + hf * 48 + g * 8) = pk;
        }
    }

    f32x4 macc[2][6];
    #pragma unroll
    for (int mt = 0; mt < 2; ++mt)
        #pragma unroll
        for (int ct = 0; ct < 6; ++ct) macc[mt][ct] = (f32x4){0.f, 0.f, 0.f, 0.f};

    for (int cc = 0; cc < 4; ++cc) {
        __syncthreads();   // hs2 ready (iter 0) / wb no longer read (iters 1..3)
        // stage w1^T rows [96cc..+95] and w2^T k-slice [*, 96cc..+95]
        for (int idx = tid * 8; idx < 9216; idx += 4096) {
            int n = idx / 96, k = idx - n * 96;
            *(bf16x8*)(wb1 + n * KP + k) = *(const bf16x8*)(wsb + 36864 + (cc * 96 + n) * 96 + k);
            *(bf16x8*)(wb2 + n * KP + k) = *(const bf16x8*)(wsb + 73728 + n * 384 + cc * 96 + k);
        }
        __syncthreads();

        // mid = gelu(hs2 @ w1_chunk + b1_chunk)
        bf16x8 a1[2][3];
        #pragma unroll
        for (int mt = 0; mt < 2; ++mt)
            #pragma unroll
            for (int s = 0; s < 3; ++s)
                a1[mt][s] = *(const bf16x8*)(hs2 + (wid * 32 + mt * 16 + lm) * KP + s * 32 + lg * 8);
        #pragma unroll
        for (int ct = 0; ct < 6; ++ct) {
            f32x4 g0 = (f32x4){0.f, 0.f, 0.f, 0.f};
            f32x4 g1 = (f32x4){0.f, 0.f, 0.f, 0.f};
            #pragma unroll
            for (int s = 0; s < 3; ++s) {
                bf16x8 bf = *(const bf16x8*)(wb1 + (ct * 16 + lm) * KP + s * 32 + lg * 8);
                g0 = mfma16(a1[0][s], bf, g0);
                g1 = mfma16(a1[1][s], bf, g1);
            }
            int col = cc * 96 + ct * 16 + lm;
            float bb = b1[col];
            #pragma unroll
            for (int j = 0; j < 4; ++j) {
                float xg = g0[j] + bb;
                mid[(wid * 32 + lg * 4 + j) * KP + ct * 16 + lm] =
                    (bf16_t)(0.5f * xg * (1.f + erff(xg * 0.70710678118654752f)));
                xg = g1[j] + bb;
                mid[(wid * 32 + 16 + lg * 4 + j) * KP + ct * 16 + lm] =
                    (bf16_t)(0.5f * xg * (1.f + erff(xg * 0.70710678118654752f)));
            }
        }
        // mlp2 partial accumulate (mid rows are wave-local; no barrier needed)
        bf16x8 a2[2][3];
        #pragma unroll
        for (int mt = 0; mt < 2; ++mt)
            #pragma unroll
            for (int s = 0; s < 3; ++s)
                a2[mt][s] = *(const bf16x8*)(mid + (wid * 32 + mt * 16 + lm) * KP + s * 32 + lg * 8);
        #pragma unroll
        for (int ct = 0; ct < 6; ++ct) {
            #pragma unroll
            for (int s = 0; s < 3; ++s) {
                bf16x8 bf = *(const bf16x8*)(wb2 + (ct * 16 + lm) * KP + s * 32 + lg * 8);
                macc[0][ct] = mfma16(a2[0][s], bf, macc[0][ct]);
                macc[1][ct] = mfma16(a2[1][s], bf, macc[1][ct]);
            }
        }
    }

    // ---- epilogue: out = x1 + ls2 * (macc + b2), in place
    #pragma unroll
    for (int mt = 0; mt < 2; ++mt) {
        #pragma unroll
        for (int ct = 0; ct < 6; ++ct) {
            int col = ct * 16 + lm;
            float bb = b2[col], l2 = ls2[col];
            #pragma unroll
            for (int j = 0; j < 4; ++j) {
                int row = wid * 32 + mt * 16 + lg * 4 + j;
                size_t a = (tok0 + row) * 96 + col;
                io[a] = io[a] + (macc[mt][ct][j] + bb) * l2;
            }
        }
    }
}

extern "C" void kernel_launch(void* const* d_in, const int* in_sizes, int n_in,
                              void* d_out, int out_size, void* d_ws, size_t ws_size,
                              hipStream_t stream) {
    const float* x    = (const float*)d_in[0];
    const float* n1g  = (const float*)d_in[1];
    const float* n1b  = (const float*)d_in[2];
    const float* qkvw = (const float*)d_in[3];
    const float* qkvb = (const float*)d_in[4];
    const float* pw   = (const float*)d_in[5];
    const float* pb   = (const float*)d_in[6];
    const float* ls1  = (const float*)d_in[7];
    const float* n2g  = (const float*)d_in[8];
    const float* n2b  = (const float*)d_in[9];
    const float* w1   = (const float*)d_in[10];
    const float* b1   = (const float*)d_in[11];
    const float* w2   = (const float*)d_in[12];
    const float* b2   = (const float*)d_in[13];
    const float* ls2  = (const float*)d_in[14];
    bf16_t* wsb = (bf16_t*)d_ws;
    float*  out = (float*)d_out;

    (void)hipFuncSetAttribute(reinterpret_cast<const void*>(attn_kernel),
                              hipFuncAttributeMaxDynamicSharedMemorySize, 156160);
    (void)hipFuncSetAttribute(reinterpret_cast<const void*>(mlp_kernel),
                              hipFuncAttributeMaxDynamicSharedMemorySize, 146432);

    prep_kernel<<<432, 256, 0, stream>>>(qkvw, pw, w1, w2, wsb);
    attn_kernel<<<256, 256, 156160, stream>>>(x, n1g, n1b, qkvb, pb, ls1, wsb, out);
    mlp_kernel<<<2048, 512, 146432, stream>>>(n2g, n2b, b1, b2, ls2, wsb, out);
}